// Round 10
// baseline (667.585 us; speedup 1.0000x reference)
//
#include <hip/hip_runtime.h>
#include <hip/hip_bf16.h>
#include <cstdint>

#define D_MODEL 768
#define NH 4
#define DH 192
#define SEQ 1024
#define BATCH 8

typedef __bf16 bf16x8 __attribute__((ext_vector_type(8)));
typedef float floatx4 __attribute__((ext_vector_type(4)));

__device__ __forceinline__ float bf2f(ushort u) {
    union { uint32_t i; float f; } x; x.i = ((uint32_t)u) << 16; return x.f;
}
__device__ __forceinline__ ushort f2bf(float f) {
    union { float f; uint32_t i; } x; x.f = f;
    uint32_t i = x.i;
    uint32_t r = (i + 0x7FFFu + ((i >> 16) & 1u)) >> 16;  // RNE
    return (ushort)r;
}

// async global->LDS, 16B per lane, LDS dest = wave-uniform base + lane*16
__device__ __forceinline__ void gl_lds16(const void* g, void* l) {
    __builtin_amdgcn_global_load_lds(
        (const __attribute__((address_space(1))) uint32_t*)g,
        (__attribute__((address_space(3))) uint32_t*)l, 16, 0, 0);
}

// ---------- LayerNorm (fp32 in). SPLIT=1: write hi+lo bf16 planes; else bf16. ----
template <int SPLIT>
__device__ __forceinline__ void ln_body(int row, int tid,
                          const float* __restrict__ x, const float* __restrict__ g,
                          const float* __restrict__ be,
                          ushort* __restrict__ y_hi, ushort* __restrict__ y_lo,
                          float* rs, float* rss) {
    const float* xr = x + (size_t)row * D_MODEL;
    float v[3];
    float s = 0.f, ss = 0.f;
#pragma unroll
    for (int i = 0; i < 3; i++) {
        float t = xr[tid + i * 256];
        v[i] = t; s += t; ss += t * t;
    }
#pragma unroll
    for (int off = 32; off > 0; off >>= 1) {
        s += __shfl_down(s, off);
        ss += __shfl_down(ss, off);
    }
    int wid = tid >> 6;
    if ((tid & 63) == 0) { rs[wid] = s; rss[wid] = ss; }
    __syncthreads();
    s = rs[0] + rs[1] + rs[2] + rs[3];
    ss = rss[0] + rss[1] + rss[2] + rss[3];
    float mu = s * (1.f / 768.f);
    float var = ss * (1.f / 768.f) - mu * mu;
    float rstd = rsqrtf(var + 1e-3f);
#pragma unroll
    for (int i = 0; i < 3; i++) {
        int d = tid + i * 256;
        float val = (v[i] - mu) * rstd * g[d] + be[d];
        ushort hi = f2bf(val);
        y_hi[(size_t)row * D_MODEL + d] = hi;
        if (SPLIT) y_lo[(size_t)row * D_MODEL + d] = f2bf(val - bf2f(hi));
    }
}

template <int SPLIT>
__global__ void ln_kernel(const float* __restrict__ x, const float* __restrict__ g,
                          const float* __restrict__ be,
                          ushort* __restrict__ y_hi, ushort* __restrict__ y_lo) {
    __shared__ float rs[4], rss[4];
    ln_body<SPLIT>(blockIdx.x, threadIdx.x, x, g, be, y_hi, y_lo, rs, rss);
}

// ---------- Fused prep: weight transposes + ln1, one launch ----------
// blocks [0,432)    : W1 [768,2304] -> hi/lo planes W1t [2304,768]
// blocks [432,576)  : W3 [768,768]   -> W3t
// blocks [576,1152) : W2 [768,3072]  -> W2t
// blocks [1152,1728): W4 [3072,768]  -> W4t
// blocks [1728,9920): ln1 row (bi-1728) — overlaps LDS-bound transpose with
// BW-bound layernorm instead of serializing at a kernel boundary.
__global__ void prep_kernel(
    const float* __restrict__ W1, ushort* __restrict__ W1t_hi, ushort* __restrict__ W1t_lo,
    const float* __restrict__ W3, ushort* __restrict__ W3t,
    const float* __restrict__ W2, ushort* __restrict__ W2t,
    const float* __restrict__ W4, ushort* __restrict__ W4t,
    const float* __restrict__ x, const float* __restrict__ g1,
    const float* __restrict__ be1, ushort* __restrict__ xn_hi, ushort* __restrict__ xn_lo) {
    __shared__ ushort th[64][65];
    __shared__ ushort tl[64][65];
    __shared__ float rs[4], rss[4];
    int bi = blockIdx.x;
    int tid = threadIdx.x;
    if (bi >= 1728) {
        ln_body<1>(bi - 1728, tid, x, g1, be1, xn_hi, xn_lo, rs, rss);
        return;
    }
    const float* W; ushort* Wt_hi; ushort* Wt_lo = nullptr; int K, N, lb;
    if (bi < 432)       { W = W1; Wt_hi = W1t_hi; Wt_lo = W1t_lo; K = 768;  N = 2304; lb = bi; }
    else if (bi < 576)  { W = W3; Wt_hi = W3t;                    K = 768;  N = 768;  lb = bi - 432; }
    else if (bi < 1152) { W = W2; Wt_hi = W2t;                    K = 768;  N = 3072; lb = bi - 576; }
    else                { W = W4; Wt_hi = W4t;                    K = 3072; N = 768;  lb = bi - 1152; }
    int nt = N >> 6;
    int bk = lb / nt, bn = lb % nt;
#pragma unroll
    for (int i = 0; i < 16; i++) {
        int lin = i * 256 + tid; int r = lin >> 6, c = lin & 63;
        float v = W[(size_t)(bk * 64 + r) * N + bn * 64 + c];
        ushort hi = f2bf(v);
        th[r][c] = hi;
        if (Wt_lo) tl[r][c] = f2bf(v - bf2f(hi));
    }
    __syncthreads();
#pragma unroll
    for (int i = 0; i < 16; i++) {
        int lin = i * 256 + tid; int r = lin >> 6, c = lin & 63;
        size_t o = (size_t)(bn * 64 + r) * K + bk * 64 + c;
        Wt_hi[o] = th[c][r];
        if (Wt_lo) Wt_lo[o] = tl[c][r];
    }
}

// ---------- split-bf16 QKV GEMM, m97 structure, ROW-affinity dispatch ----------
// Grid (64 rows, 18 cols), x-major => bid%8 = row%8 => each XCD holds 8 fixed
// A row-panels (3.1MB hi+lo, L2-resident); B streams once per XCD.
// [measured r8: FETCH 216->92MB ≈ compulsory — locality model confirmed]
// Uniform 3-pass all blocks (vblk desync lesson, rounds 5/6). 5 blocks/CU
// (32KB x 5 = 160KB exactly). present = pure output -> nontemporal stores.
__global__ __launch_bounds__(256, 5) void gemm_qkv_split(
    const ushort* __restrict__ Ah, const ushort* __restrict__ Al,
    const ushort* __restrict__ Bh, const ushort* __restrict__ Bl,
    const float* __restrict__ bias,
    ushort* __restrict__ Qhg, ushort* __restrict__ Qlg, float* __restrict__ present,
    ushort* __restrict__ Khg, ushort* __restrict__ Klg, ushort* __restrict__ Vtg) {
    const int K = 768;
    __shared__ __align__(16) __bf16 sAh[128][32];
    __shared__ __align__(16) __bf16 sAl[128][32];
    __shared__ __align__(16) __bf16 sBh[128][32];
    __shared__ __align__(16) __bf16 sBl[128][32];
    int tid = threadIdx.x;
    int rowBase = blockIdx.x << 7;   // rows on x (fast axis) -> XCD row-affinity
    int colBase = blockIdx.y << 7;

    int wave = tid >> 6, lane = tid & 63;
    int wm = (wave & 1) << 6, wn = (wave >> 1) << 6;
    int lrow = lane & 15, q = lane >> 4;
    int lkswz = ((q ^ ((lrow >> 1) & 3)) << 3);
    floatx4 acc[4][4] = {};

    int srow = lane >> 2;
    int schunk = (lane & 3) ^ ((lane >> 3) & 3);
    const ushort* Ah0 = Ah + (size_t)(rowBase + wave * 32 + srow) * K + schunk * 8;
    const ushort* Al0 = Al + (size_t)(rowBase + wave * 32 + srow) * K + schunk * 8;
    const ushort* Bh0 = Bh + (size_t)(colBase + wave * 32 + srow) * K + schunk * 8;
    const ushort* Bl0 = Bl + (size_t)(colBase + wave * 32 + srow) * K + schunk * 8;
    const size_t r16 = (size_t)16 * K;
    int wr = wave * 32;

    const int nt = K >> 5;
    for (int t = 0; t < nt; t++) {
        if (t) __syncthreads();          // readers of previous tile done
        int k0 = t << 5;
        gl_lds16(Ah0 + k0, &sAh[wr][0]);  gl_lds16(Ah0 + r16 + k0, &sAh[wr + 16][0]);
        gl_lds16(Al0 + k0, &sAl[wr][0]);  gl_lds16(Al0 + r16 + k0, &sAl[wr + 16][0]);
        gl_lds16(Bh0 + k0, &sBh[wr][0]);  gl_lds16(Bh0 + r16 + k0, &sBh[wr + 16][0]);
        gl_lds16(Bl0 + k0, &sBl[wr][0]);  gl_lds16(Bl0 + r16 + k0, &sBl[wr + 16][0]);
        __syncthreads();                 // vmcnt(0) drain: tile visible
        bf16x8 afh[4], afl[4], bvh[4], bvl[4];
#pragma unroll
        for (int i = 0; i < 4; i++) {
            afh[i] = *(const bf16x8*)&sAh[wm + i * 16 + lrow][lkswz];
            afl[i] = *(const bf16x8*)&sAl[wm + i * 16 + lrow][lkswz];
        }
#pragma unroll
        for (int jj = 0; jj < 4; jj++) {
            bvh[jj] = *(const bf16x8*)&sBh[wn + jj * 16 + lrow][lkswz];
            bvl[jj] = *(const bf16x8*)&sBl[wn + jj * 16 + lrow][lkswz];
        }
#pragma unroll
        for (int i = 0; i < 4; i++)
#pragma unroll
            for (int jj = 0; jj < 4; jj++) {
                acc[i][jj] = __builtin_amdgcn_mfma_f32_16x16x32_bf16(afh[i], bvh[jj], acc[i][jj], 0, 0, 0);
                acc[i][jj] = __builtin_amdgcn_mfma_f32_16x16x32_bf16(afh[i], bvl[jj], acc[i][jj], 0, 0, 0);
                acc[i][jj] = __builtin_amdgcn_mfma_f32_16x16x32_bf16(afl[i], bvh[jj], acc[i][jj], 0, 0, 0);
            }
    }

    int cr = (lane >> 4) << 2;
    int cc = lane & 15;
#pragma unroll
    for (int jj = 0; jj < 4; jj++) {
        int col = colBase + wn + jj * 16 + cc;
        float bvs = bias[col];
        if (colBase < 768) {            // ---- Q tile -> Qhg/Qlg bf16 planes ----
#pragma unroll
            for (int i = 0; i < 4; i++) {
                int row0 = rowBase + wm + i * 16 + cr;
#pragma unroll
                for (int r = 0; r < 4; r++) {
                    float v = acc[i][jj][r] + bvs;
                    ushort hi = f2bf(v);
                    Qhg[(size_t)(row0 + r) * 768 + col] = hi;
                    Qlg[(size_t)(row0 + r) * 768 + col] = f2bf(v - bf2f(hi));
                }
            }
        } else if (colBase < 1536) {    // ---- K tile -> present + scaled Khg/Klg ----
            int kc = col - 768;
            int h = kc / DH, d = kc - h * DH;
#pragma unroll
            for (int i = 0; i < 4; i++) {
                int row0 = rowBase + wm + i * 16 + cr;
#pragma unroll
                for (int r = 0; r < 4; r++) {
                    int row = row0 + r;
                    int b = row >> 10, s = row & 1023;
                    float v = acc[i][jj][r] + bvs;
                    __builtin_nontemporal_store(v,
                        &present[((size_t)((b * 2) * NH + h) * SEQ + s) * DH + d]);
                    float sv = v * 13.856406460551018f;   // sqrt(192) fold into K
                    ushort hi = f2bf(sv);
                    Khg[(size_t)row * 768 + kc] = hi;
                    Klg[(size_t)row * 768 + kc] = f2bf(sv - bf2f(hi));
                }
            }
        } else {                        // ---- V tile -> present + Vtg (transposed) --
            int vc = col - 1536;
            int h = vc / DH, d = vc - h * DH;
#pragma unroll
            for (int i = 0; i < 4; i++) {
                int row0 = rowBase + wm + i * 16 + cr;
#pragma unroll
                for (int r = 0; r < 4; r++) {
                    int row = row0 + r;
                    int b = row >> 10, s = row & 1023;
                    float v = acc[i][jj][r] + bvs;
                    __builtin_nontemporal_store(v,
                        &present[((size_t)((b * 2 + 1) * NH + h) * SEQ + s) * DH + d]);
                    Vtg[((size_t)b * 768 + vc) * 1024 + s] = f2bf(v);
                }
            }
        }
    }
}

// ---------- MFMA GEMM (bf16 in): C = A@Bt^T + bias (+GELU)(+fp32 res) ----------
// global_load_lds staging, [2][128][32] linear LDS, XOR-swizzled source/read,
// double-buffered, one barrier per k-step, 5 blocks/CU.
// SWAPG=1: rows on blockIdx.x (XCD row-affinity). NT=1: nontemporal C store
// (pure-output tensors only — never re-read).
template <int GELU, int RES, int OUTF32, int SWAPG, int NT>
__global__ __launch_bounds__(256, 5) void gemm_bt(
    const ushort* __restrict__ A, const ushort* __restrict__ Bt,
    const float* __restrict__ bias, const float* __restrict__ resid,
    void* __restrict__ Cout, int M, int N, int K) {
    __shared__ __align__(16) __bf16 sA[2][128][32];
    __shared__ __align__(16) __bf16 sB[2][128][32];
    int tid = threadIdx.x;
    int rowBase = (SWAPG ? blockIdx.x : blockIdx.y) << 7;
    int colBase = (SWAPG ? blockIdx.y : blockIdx.x) << 7;

    int wave = tid >> 6, lane = tid & 63;
    int wm = (wave & 1) << 6, wn = (wave >> 1) << 6;
    int lrow = lane & 15, q = lane >> 4;
    int lkswz = ((q ^ ((lrow >> 1) & 3)) << 3);
    floatx4 acc[4][4] = {};

    int srow = lane >> 2;
    int schunk = (lane & 3) ^ ((lane >> 3) & 3);
    const ushort* Ag0 = A + (size_t)(rowBase + wave * 32 + srow) * K + schunk * 8;
    const ushort* Bg0 = Bt + (size_t)(colBase + wave * 32 + srow) * K + schunk * 8;
    const size_t r16 = (size_t)16 * K;
    int wr = wave * 32;

    gl_lds16(Ag0, &sA[0][wr][0]);  gl_lds16(Ag0 + r16, &sA[0][wr + 16][0]);
    gl_lds16(Bg0, &sB[0][wr][0]);  gl_lds16(Bg0 + r16, &sB[0][wr + 16][0]);
    __syncthreads();

    int nt = K >> 5;
    for (int t = 0; t < nt; t++) {
        int cur = t & 1, nb = cur ^ 1;
        if (t + 1 < nt) {
            int k0 = (t + 1) << 5;
            gl_lds16(Ag0 + k0, &sA[nb][wr][0]);  gl_lds16(Ag0 + r16 + k0, &sA[nb][wr + 16][0]);
            gl_lds16(Bg0 + k0, &sB[nb][wr][0]);  gl_lds16(Bg0 + r16 + k0, &sB[nb][wr + 16][0]);
        }
        bf16x8 af[4], bv[4];
#pragma unroll
        for (int i = 0; i < 4; i++) af[i] = *(const bf16x8*)&sA[cur][wm + i * 16 + lrow][lkswz];
#pragma unroll
        for (int jj = 0; jj < 4; jj++) bv[jj] = *(const bf16x8*)&sB[cur][wn + jj * 16 + lrow][lkswz];
#pragma unroll
        for (int i = 0; i < 4; i++)
#pragma unroll
            for (int jj = 0; jj < 4; jj++)
                acc[i][jj] = __builtin_amdgcn_mfma_f32_16x16x32_bf16(af[i], bv[jj], acc[i][jj], 0, 0, 0);
        __syncthreads();
    }
    int cr = (lane >> 4) << 2;
    int cc = lane & 15;
#pragma unroll
    for (int jj = 0; jj < 4; jj++) {
        int col = colBase + wn + jj * 16 + cc;
        float bvs = bias[col];
#pragma unroll
        for (int i = 0; i < 4; i++) {
            int row0 = rowBase + wm + i * 16 + cr;
#pragma unroll
            for (int r = 0; r < 4; r++) {
                int row = row0 + r;
                float v = acc[i][jj][r] + bvs;
                if (GELU) {
                    // 0.5u(1+tanh(z)) == u*sigmoid(2z), exact identity; HW exp
                    float u = v;
                    float z2 = -1.5957691216057308f * (u + 0.044715f * u * u * u);
                    v = u / (1.f + __expf(z2));
                }
                if (RES) v += resid[(size_t)row * N + col];
                if (OUTF32) {
                    float* p = &((float*)Cout)[(size_t)row * N + col];
                    if (NT) __builtin_nontemporal_store(v, p);
                    else *p = v;
                } else {
                    ((ushort*)Cout)[(size_t)row * N + col] = f2bf(v);
                }
            }
        }
    }
}

// ---------- flash attention (MFMA), balanced paired q-tiles + prefetch ----------
// Q pre-split bf16 (Qhg/Qlg); K pre-scaled by sqrt(192) at qkv time.
// XCD co-location remap (r8): bi%8 = (b*4+h)%8 — group's KV shared in one L2.
// T5 setprio around MFMA clusters (m191: +4-7% on phase-diverse attn waves).
__global__ __launch_bounds__(512, 2) void attn_flash(
    const ushort* __restrict__ Qhg, const ushort* __restrict__ Qlg,
    const ushort* __restrict__ Khg, const ushort* __restrict__ Klg,
    const ushort* __restrict__ Vtg, ushort* __restrict__ attn2) {
    int bi = blockIdx.x;
    int xc = bi & 7;
    int yc = bi >> 3;
    int j  = yc & 7;
    int g  = ((yc >> 3) << 3) | xc;   // group in [0,32): g = b*4 + h
    int h  = g & 3;
    int b  = g >> 2;
    int tid = threadIdx.x;
    int wave = tid >> 6, lane = tid & 63;
    int l15 = lane & 15, quad = lane >> 4;
    int tile = (wave < 4) ? (15 - j) : j;
    int w16 = wave & 3;
    int s0 = tile << 6;
    int its = 2 * (15 - j) + 2;
    int myKt = (s0 + w16 * 16 + 15) >> 5;

    __shared__ __align__(16) __bf16 sKh[2][32][200];
    __shared__ __align__(16) __bf16 sKl[2][32][200];
    __shared__ __align__(16) __bf16 sVt[2][192][40];
    __shared__ __align__(16) ushort sP[8][16][40];

    const bool lo_half = (tid < 256);
    const int kr0 = tid / 24, ke0 = (tid % 24) * 8;
    const int c1 = lo_half ? (512 + tid) : (256 + tid);
    const int kr1 = c1 / 24, ke1 = (c1 % 24) * 8;
    const int vd0 = tid >> 2, ve0 = (tid & 3) * 8;
    const int vd1 = (512 + tid) >> 2, ve1 = ((512 + tid) & 3) * 8;

    const ushort* Khb = Khg + (size_t)(b * 1024) * 768 + h * 192;
    const ushort* Klb = Klg + (size_t)(b * 1024) * 768 + h * 192;
    const ushort* Vtb = Vtg + ((size_t)(b * 768) + h * 192) * 1024;
    const ushort* Bb = lo_half ? Khb : Klb;
    __bf16* pKB = lo_half ? &sKh[0][kr1][ke1] : &sKl[0][kr1][ke1];

    uint4 rA, rB, rC, rD, rE;

    rA = *(const uint4*)(Khb + (size_t)kr0 * 768 + ke0);
    rC = *(const uint4*)(Klb + (size_t)kr0 * 768 + ke0);
    rB = *(const uint4*)(Bb + (size_t)kr1 * 768 + ke1);
    rD = *(const uint4*)(Vtb + (size_t)vd0 * 1024 + ve0);
    if (lo_half) rE = *(const uint4*)(Vtb + (size_t)vd1 * 1024 + ve1);

    bf16x8 qh[6], ql[6];
    {
        int qrow = s0 + w16 * 16 + l15;
        const ushort* qph = Qhg + (size_t)(b * SEQ + qrow) * 768 + h * DH + quad * 8;
        const ushort* qpl = Qlg + (size_t)(b * SEQ + qrow) * 768 + h * DH + quad * 8;
#pragma unroll
        for (int dt = 0; dt < 6; dt++) {
            qh[dt] = *(const bf16x8*)(qph + dt * 32);
            ql[dt] = *(const bf16x8*)(qpl + dt * 32);
        }
    }

    floatx4 O[12] = {};
    float m_run[4], l_run[4];
#pragma unroll
    for (int r = 0; r < 4; r++) { m_run[r] = -1e30f; l_run[r] = 0.f; }

    *(uint4*)&sKh[0][kr0][ke0] = rA;
    *(uint4*)&sKl[0][kr0][ke0] = rC;
    *(uint4*)(pKB) = rB;
    *(uint4*)&sVt[0][vd0][ve0] = rD;
    if (lo_half) *(uint4*)&sVt[0][vd1][ve1] = rE;
    __syncthreads();

    for (int kt = 0; kt < its; kt++) {
        int cur = kt & 1;
        bool pfetch = (kt + 1 < its);
        if (pfetch) {
            int koff = (kt + 1) * 32;
            rA = *(const uint4*)(Khb + (size_t)(koff + kr0) * 768 + ke0);
            rC = *(const uint4*)(Klb + (size_t)(koff + kr0) * 768 + ke0);
            rB = *(const uint4*)(Bb + (size_t)(koff + kr1) * 768 + ke1);
            rD = *(const uint4*)(Vtb + (size_t)vd0 * 1024 + koff + ve0);
            if (lo_half) rE = *(const uint4*)(Vtb + (size_t)vd1 * 1024 + koff + ve1);
        }
        if (kt <= myKt) {
            floatx4 S0 = {}, S1 = {};
            __builtin_amdgcn_s_setprio(1);
#pragma unroll
            for (int dt = 0; dt < 6; dt++) {
                bf16x8 k0h = *(const bf16x8*)&sKh[cur][l15][dt * 32 + quad * 8];
                bf16x8 k0l = *(const bf16x8*)&sKl[cur][l15][dt * 32 + quad * 8];
                bf16x8 k1h = *(const bf16x8*)&sKh[cur][16 + l15][dt * 32 + quad * 8];
                bf16x8 k1l = *(const bf16x8*)&sKl[cur][16 + l15][dt * 32 + quad * 8];
                S0 = __builtin_amdgcn_mfma_f32_16x16x32_bf16(qh[dt], k0h, S0, 0, 0, 0);
                S0 = __builtin_amdgcn_mfma_f32_16x16x32_bf16(qh[dt], k0l, S0, 0, 0, 0);
                S0 = __builtin_amdgcn_mfma_f32_16x16x32_bf16(ql[dt], k0h, S0, 0, 0, 0);
                S1 = __builtin_amdgcn_mfma_f32_16x16x32_bf16(qh[dt], k1h, S1, 0, 0, 0);
                S1 = __builtin_amdgcn_mfma_f32_16x16x32_bf16(qh[dt], k1l, S1, 0, 0, 0);
                S1 = __builtin_amdgcn_mfma_f32_16x16x32_bf16(ql[dt], k1h, S1, 0, 0, 0);
            }
            __builtin_amdgcn_s_setprio(0);
            int qg = s0 + w16 * 16 + quad * 4;
            int colb = kt * 32 + l15;
            float mt[4];
#pragma unroll
            for (int r = 0; r < 4; r++) {
                float a = (colb <= qg + r) ? S0[r] : -1e30f;
                float c = (colb + 16 <= qg + r) ? S1[r] : -1e30f;
                S0[r] = a; S1[r] = c;
                mt[r] = fmaxf(a, c);
            }
#pragma unroll
            for (int m = 1; m <= 8; m <<= 1)
#pragma unroll
                for (int r = 0; r < 4; r++) mt[r] = fmaxf(mt[r], __shfl_xor(mt[r], m));
            float alpha[4], rsum[4], P0[4], P1[4];
#pragma unroll
            for (int r = 0; r < 4; r++) {
                float mn = fmaxf(m_run[r], mt[r]);
                alpha[r] = __expf(m_run[r] - mn);
                m_run[r] = mn;
                P0[r] = __expf(S0[r] - mn);
                P1[r] = __expf(S1[r] - mn);
                rsum[r] = P0[r] + P1[r];
            }
#pragma unroll
            for (int m = 1; m <= 8; m <<= 1)
#pragma unroll
                for (int r = 0; r < 4; r++) rsum[r] += __shfl_xor(rsum[r], m);
#pragma unroll
            for (int r = 0; r < 4; r++) l_run[r] = l_run[r] * alpha[r] + rsum[r];
#pragma unroll
            for (int t = 0; t < 12; t++)
#pragma unroll
                for (int r = 0; r < 4; r++) O[t][r] *= alpha[r];
#pragma unroll
            for (int r = 0; r < 4; r++) {
                sP[wave][quad * 4 + r][l15]      = f2bf(P0[r]);
                sP[wave][quad * 4 + r][16 + l15] = f2bf(P1[r]);
            }
            bf16x8 pfrag = *(const bf16x8*)&sP[wave][l15][quad * 8];
            __builtin_amdgcn_s_setprio(1);
#pragma unroll
            for (int t = 0; t < 12; t++) {
                bf16x8 vf = *(const bf16x8*)&sVt[cur][t * 16 + l15][quad * 8];
                O[t] = __builtin_amdgcn_mfma_f32_16x16x32_bf16(pfrag, vf, O[t], 0, 0, 0);
            }
            __builtin_amdgcn_s_setprio(0);
        }
        if (pfetch) {
            int nb = cur ^ 1;
            *(uint4*)&sKh[nb][kr0][ke0] = rA;
            *(uint4*)&sKl[nb][kr0][ke0] = rC;
            *(uint4*)(pKB + nb * 6400) = rB;
            *(uint4*)&sVt[nb][vd0][ve0] = rD;
            if (lo_half) *(uint4*)&sVt[nb][vd1][ve1] = rE;
        }
        __syncthreads();
    }

    float inv[4];
#pragma unroll
    for (int r = 0; r < 4; r++) inv[r] = 1.f / l_run[r];
    int qrow = s0 + w16 * 16 + quad * 4;
#pragma unroll
    for (int t = 0; t < 12; t++)
#pragma unroll
        for (int r = 0; r < 4; r++)
            attn2[(size_t)(b * SEQ + qrow + r) * D_MODEL + h * DH + t * 16 + l15] =
                f2bf(O[t][r] * inv[r]);
}

extern "C" void kernel_launch(void* const* d_in, const int* in_sizes, int n_in,
                              void* d_out, int out_size, void* d_ws, size_t ws_size,
                              hipStream_t stream) {
    const float* x  = (const float*)d_in[0];
    const float* W1 = (const float*)d_in[2];
    const float* b1 = (const float*)d_in[3];
    const float* W3 = (const float*)d_in[4];
    const float* b3 = (const float*)d_in[5];
    const float* W2 = (const float*)d_in[6];
    const float* b2 = (const float*)d_in[7];
    const float* W4 = (const float*)d_in[8];
    const float* b4 = (const float*)d_in[9];
    const float* g1 = (const float*)d_in[10];
    const float* be1 = (const float*)d_in[11];
    const float* g2 = (const float*)d_in[12];
    const float* be2 = (const float*)d_in[13];

    // ---- ws layout, lifetime-aliased ----
    char* ws = (char*)d_ws;
    ushort* W1t_hi = (ushort*)(ws + 0);            // -> 3,538,944
    ushort* W1t_lo = (ushort*)(ws + 3538944);      // -> 7,077,888
    ushort* W3t    = (ushort*)(ws + 7077888);      // -> 8,257,536
    ushort* W2t    = (ushort*)(ws + 8257536);      // -> 12,976,128
    ushort* W4t    = (ushort*)(ws + 12976128);     // -> 17,694,720
    ushort* xn_hi  = (ushort*)(ws + 17694720);     // -> 30,277,632 (then attn2)
    ushort* attn2  = (ushort*)(ws + 17694720);
    ushort* xn_lo  = (ushort*)(ws + 30277632);     // -> 42,860,544 (then xn2)
    ushort* xn2    = (ushort*)(ws + 30277632);
    ushort* Qhg    = (ushort*)(ws + 42860544);     // -> 55,443,456 (dead after attn)
    ushort* Qlg    = (ushort*)(ws + 55443456);     // -> 68,026,368 (dead after attn)
    ushort* hbuf   = (ushort*)(ws + 42860544);     // ff1 out: -> 93,192,192
    ushort* Khg    = (ushort*)(ws + 68026368);     // -> 80,609,280 (dead after attn)
    ushort* Klg    = (ushort*)(ws + 80609280);     // -> 93,192,192 (dead after attn)
    ushort* Vtg    = (ushort*)(ws + 93192192);     // -> 105,775,104 (dead after attn)
    float*  x1     = (float*)(ws + 105775104);     // -> 130,940,928

    float* out0 = (float*)d_out;
    float* present = out0 + 6291456;

    // fused: weight transposes (1728 blocks) + ln1 (8192 blocks)
    prep_kernel<<<1728 + 8192, 256, 0, stream>>>(
        W1, W1t_hi, W1t_lo, W3, W3t, W2, W2t, W4, W4t, x, g1, be1, xn_hi, xn_lo);
    // rows on x (fast axis): bid%8 = row%8 -> per-XCD A-panel residency
    gemm_qkv_split<<<dim3(8192 / 128, 2304 / 128), 256, 0, stream>>>(
        xn_hi, xn_lo, W1t_hi, W1t_lo, b1, Qhg, Qlg, present, Khg, Klg, Vtg);
    attn_flash<<<BATCH * NH * 8, 512, 0, stream>>>(Qhg, Qlg, Khg, Klg, Vtg, attn2);
    // proj: SWAPG=1 (A/XCD = 1.6MB, L2-fit); x1 re-read -> cached stores
    gemm_bt<0, 1, 1, 1, 0><<<dim3(8192 / 128, 768 / 128), 256, 0, stream>>>(
        attn2, W3t, b3, x, x1, 8192, 768, 768);
    ln_kernel<0><<<8192, 256, 0, stream>>>(x1, g2, be2, xn2, nullptr);
    // ff1: SWAPG=1 (A/XCD = 1.6MB, L2-fit); hbuf re-read -> cached
    gemm_bt<1, 0, 0, 1, 0><<<dim3(8192 / 128, 3072 / 128), 256, 0, stream>>>(
        xn2, W2t, b2, nullptr, hbuf, 8192, 3072, 768);
    // ff2: SWAPG=1 row-affinity; out0 is final output -> nontemporal stores
    gemm_bt<0, 1, 1, 1, 1><<<dim3(8192 / 128, 3072 / 128 / 4), 256, 0, stream>>>(
        hbuf, W4t, b4, x1, out0, 8192, 768, 3072);
}

// Round 11
// 474.665 us; speedup vs baseline: 1.4064x; 1.4064x over previous
//
#include <hip/hip_runtime.h>
#include <hip/hip_bf16.h>
#include <cstdint>

#define D_MODEL 768
#define NH 4
#define DH 192
#define SEQ 1024
#define BATCH 8

typedef __bf16 bf16x8 __attribute__((ext_vector_type(8)));
typedef float floatx4 __attribute__((ext_vector_type(4)));

__device__ __forceinline__ float bf2f(ushort u) {
    union { uint32_t i; float f; } x; x.i = ((uint32_t)u) << 16; return x.f;
}
__device__ __forceinline__ ushort f2bf(float f) {
    union { float f; uint32_t i; } x; x.f = f;
    uint32_t i = x.i;
    uint32_t r = (i + 0x7FFFu + ((i >> 16) & 1u)) >> 16;  // RNE
    return (ushort)r;
}

// async global->LDS, 16B per lane, LDS dest = wave-uniform base + lane*16
__device__ __forceinline__ void gl_lds16(const void* g, void* l) {
    __builtin_amdgcn_global_load_lds(
        (const __attribute__((address_space(1))) uint32_t*)g,
        (__attribute__((address_space(3))) uint32_t*)l, 16, 0, 0);
}

// ---------- LayerNorm (fp32 in). SPLIT=1: write hi+lo bf16 planes; else bf16. ----
template <int SPLIT>
__device__ __forceinline__ void ln_body(int row, int tid,
                          const float* __restrict__ x, const float* __restrict__ g,
                          const float* __restrict__ be,
                          ushort* __restrict__ y_hi, ushort* __restrict__ y_lo,
                          float* rs, float* rss) {
    const float* xr = x + (size_t)row * D_MODEL;
    float v[3];
    float s = 0.f, ss = 0.f;
#pragma unroll
    for (int i = 0; i < 3; i++) {
        float t = xr[tid + i * 256];
        v[i] = t; s += t; ss += t * t;
    }
#pragma unroll
    for (int off = 32; off > 0; off >>= 1) {
        s += __shfl_down(s, off);
        ss += __shfl_down(ss, off);
    }
    int wid = tid >> 6;
    if ((tid & 63) == 0) { rs[wid] = s; rss[wid] = ss; }
    __syncthreads();
    s = rs[0] + rs[1] + rs[2] + rs[3];
    ss = rss[0] + rss[1] + rss[2] + rss[3];
    float mu = s * (1.f / 768.f);
    float var = ss * (1.f / 768.f) - mu * mu;
    float rstd = rsqrtf(var + 1e-3f);
#pragma unroll
    for (int i = 0; i < 3; i++) {
        int d = tid + i * 256;
        float val = (v[i] - mu) * rstd * g[d] + be[d];
        ushort hi = f2bf(val);
        y_hi[(size_t)row * D_MODEL + d] = hi;
        if (SPLIT) y_lo[(size_t)row * D_MODEL + d] = f2bf(val - bf2f(hi));
    }
}

template <int SPLIT>
__global__ void ln_kernel(const float* __restrict__ x, const float* __restrict__ g,
                          const float* __restrict__ be,
                          ushort* __restrict__ y_hi, ushort* __restrict__ y_lo) {
    __shared__ float rs[4], rss[4];
    ln_body<SPLIT>(blockIdx.x, threadIdx.x, x, g, be, y_hi, y_lo, rs, rss);
}

// ---------- Fused prep: weight transposes + ln1, one launch ----------
__global__ void prep_kernel(
    const float* __restrict__ W1, ushort* __restrict__ W1t_hi, ushort* __restrict__ W1t_lo,
    const float* __restrict__ W3, ushort* __restrict__ W3t,
    const float* __restrict__ W2, ushort* __restrict__ W2t,
    const float* __restrict__ W4, ushort* __restrict__ W4t,
    const float* __restrict__ x, const float* __restrict__ g1,
    const float* __restrict__ be1, ushort* __restrict__ xn_hi, ushort* __restrict__ xn_lo) {
    __shared__ ushort th[64][65];
    __shared__ ushort tl[64][65];
    __shared__ float rs[4], rss[4];
    int bi = blockIdx.x;
    int tid = threadIdx.x;
    if (bi >= 1728) {
        ln_body<1>(bi - 1728, tid, x, g1, be1, xn_hi, xn_lo, rs, rss);
        return;
    }
    const float* W; ushort* Wt_hi; ushort* Wt_lo = nullptr; int K, N, lb;
    if (bi < 432)       { W = W1; Wt_hi = W1t_hi; Wt_lo = W1t_lo; K = 768;  N = 2304; lb = bi; }
    else if (bi < 576)  { W = W3; Wt_hi = W3t;                    K = 768;  N = 768;  lb = bi - 432; }
    else if (bi < 1152) { W = W2; Wt_hi = W2t;                    K = 768;  N = 3072; lb = bi - 576; }
    else                { W = W4; Wt_hi = W4t;                    K = 3072; N = 768;  lb = bi - 1152; }
    int nt = N >> 6;
    int bk = lb / nt, bn = lb % nt;
#pragma unroll
    for (int i = 0; i < 16; i++) {
        int lin = i * 256 + tid; int r = lin >> 6, c = lin & 63;
        float v = W[(size_t)(bk * 64 + r) * N + bn * 64 + c];
        ushort hi = f2bf(v);
        th[r][c] = hi;
        if (Wt_lo) tl[r][c] = f2bf(v - bf2f(hi));
    }
    __syncthreads();
#pragma unroll
    for (int i = 0; i < 16; i++) {
        int lin = i * 256 + tid; int r = lin >> 6, c = lin & 63;
        size_t o = (size_t)(bn * 64 + r) * K + bk * 64 + c;
        Wt_hi[o] = th[c][r];
        if (Wt_lo) Wt_lo[o] = tl[c][r];
    }
}

// ---------- split-bf16 QKV GEMM, m97 structure, ROW-affinity dispatch ----------
// Grid (64 rows, 18 cols), x-major => bid%8 = row%8 => each XCD holds 8 fixed
// A row-panels (3.1MB hi+lo, L2-resident); B streams once per XCD.
// [measured r8: FETCH 216->92MB ≈ compulsory] 4 blocks/CU, PLAIN stores
// (r9 lesson: nontemporal on scattered partial-line writes => RMW blowup,
// WRITE 140->626MB). Uniform 3-pass all blocks (vblk desync lesson r5/6).
__global__ __launch_bounds__(256, 4) void gemm_qkv_split(
    const ushort* __restrict__ Ah, const ushort* __restrict__ Al,
    const ushort* __restrict__ Bh, const ushort* __restrict__ Bl,
    const float* __restrict__ bias,
    ushort* __restrict__ Qhg, ushort* __restrict__ Qlg, float* __restrict__ present,
    ushort* __restrict__ Khg, ushort* __restrict__ Klg, ushort* __restrict__ Vtg) {
    const int K = 768;
    __shared__ __align__(16) __bf16 sAh[128][32];
    __shared__ __align__(16) __bf16 sAl[128][32];
    __shared__ __align__(16) __bf16 sBh[128][32];
    __shared__ __align__(16) __bf16 sBl[128][32];
    int tid = threadIdx.x;
    int rowBase = blockIdx.x << 7;   // rows on x (fast axis) -> XCD row-affinity
    int colBase = blockIdx.y << 7;

    int wave = tid >> 6, lane = tid & 63;
    int wm = (wave & 1) << 6, wn = (wave >> 1) << 6;
    int lrow = lane & 15, q = lane >> 4;
    int lkswz = ((q ^ ((lrow >> 1) & 3)) << 3);
    floatx4 acc[4][4] = {};

    int srow = lane >> 2;
    int schunk = (lane & 3) ^ ((lane >> 3) & 3);
    const ushort* Ah0 = Ah + (size_t)(rowBase + wave * 32 + srow) * K + schunk * 8;
    const ushort* Al0 = Al + (size_t)(rowBase + wave * 32 + srow) * K + schunk * 8;
    const ushort* Bh0 = Bh + (size_t)(colBase + wave * 32 + srow) * K + schunk * 8;
    const ushort* Bl0 = Bl + (size_t)(colBase + wave * 32 + srow) * K + schunk * 8;
    const size_t r16 = (size_t)16 * K;
    int wr = wave * 32;

    const int nt = K >> 5;
    for (int t = 0; t < nt; t++) {
        if (t) __syncthreads();          // readers of previous tile done
        int k0 = t << 5;
        gl_lds16(Ah0 + k0, &sAh[wr][0]);  gl_lds16(Ah0 + r16 + k0, &sAh[wr + 16][0]);
        gl_lds16(Al0 + k0, &sAl[wr][0]);  gl_lds16(Al0 + r16 + k0, &sAl[wr + 16][0]);
        gl_lds16(Bh0 + k0, &sBh[wr][0]);  gl_lds16(Bh0 + r16 + k0, &sBh[wr + 16][0]);
        gl_lds16(Bl0 + k0, &sBl[wr][0]);  gl_lds16(Bl0 + r16 + k0, &sBl[wr + 16][0]);
        __syncthreads();                 // vmcnt(0) drain: tile visible
        bf16x8 afh[4], afl[4], bvh[4], bvl[4];
#pragma unroll
        for (int i = 0; i < 4; i++) {
            afh[i] = *(const bf16x8*)&sAh[wm + i * 16 + lrow][lkswz];
            afl[i] = *(const bf16x8*)&sAl[wm + i * 16 + lrow][lkswz];
        }
#pragma unroll
        for (int jj = 0; jj < 4; jj++) {
            bvh[jj] = *(const bf16x8*)&sBh[wn + jj * 16 + lrow][lkswz];
            bvl[jj] = *(const bf16x8*)&sBl[wn + jj * 16 + lrow][lkswz];
        }
#pragma unroll
        for (int i = 0; i < 4; i++)
#pragma unroll
            for (int jj = 0; jj < 4; jj++) {
                acc[i][jj] = __builtin_amdgcn_mfma_f32_16x16x32_bf16(afh[i], bvh[jj], acc[i][jj], 0, 0, 0);
                acc[i][jj] = __builtin_amdgcn_mfma_f32_16x16x32_bf16(afh[i], bvl[jj], acc[i][jj], 0, 0, 0);
                acc[i][jj] = __builtin_amdgcn_mfma_f32_16x16x32_bf16(afl[i], bvh[jj], acc[i][jj], 0, 0, 0);
            }
    }

    int cr = (lane >> 4) << 2;
    int cc = lane & 15;
#pragma unroll
    for (int jj = 0; jj < 4; jj++) {
        int col = colBase + wn + jj * 16 + cc;
        float bvs = bias[col];
        if (colBase < 768) {            // ---- Q tile -> Qhg/Qlg bf16 planes ----
#pragma unroll
            for (int i = 0; i < 4; i++) {
                int row0 = rowBase + wm + i * 16 + cr;
#pragma unroll
                for (int r = 0; r < 4; r++) {
                    float v = acc[i][jj][r] + bvs;
                    ushort hi = f2bf(v);
                    Qhg[(size_t)(row0 + r) * 768 + col] = hi;
                    Qlg[(size_t)(row0 + r) * 768 + col] = f2bf(v - bf2f(hi));
                }
            }
        } else if (colBase < 1536) {    // ---- K tile -> present + scaled Khg/Klg ----
            int kc = col - 768;
            int h = kc / DH, d = kc - h * DH;
#pragma unroll
            for (int i = 0; i < 4; i++) {
                int row0 = rowBase + wm + i * 16 + cr;
#pragma unroll
                for (int r = 0; r < 4; r++) {
                    int row = row0 + r;
                    int b = row >> 10, s = row & 1023;
                    float v = acc[i][jj][r] + bvs;
                    present[((size_t)((b * 2) * NH + h) * SEQ + s) * DH + d] = v;
                    float sv = v * 13.856406460551018f;   // sqrt(192) fold into K
                    ushort hi = f2bf(sv);
                    Khg[(size_t)row * 768 + kc] = hi;
                    Klg[(size_t)row * 768 + kc] = f2bf(sv - bf2f(hi));
                }
            }
        } else {                        // ---- V tile -> present + Vtg (transposed) --
            int vc = col - 1536;
            int h = vc / DH, d = vc - h * DH;
#pragma unroll
            for (int i = 0; i < 4; i++) {
                int row0 = rowBase + wm + i * 16 + cr;
#pragma unroll
                for (int r = 0; r < 4; r++) {
                    int row = row0 + r;
                    int b = row >> 10, s = row & 1023;
                    float v = acc[i][jj][r] + bvs;
                    present[((size_t)((b * 2 + 1) * NH + h) * SEQ + s) * DH + d] = v;
                    Vtg[((size_t)b * 768 + vc) * 1024 + s] = f2bf(v);
                }
            }
        }
    }
}

// ---------- MFMA GEMM (bf16 in): C = A@Bt^T + bias (+GELU)(+fp32 res) ----------
// global_load_lds staging, [2][128][32] linear LDS, XOR-swizzled source/read,
// double-buffered, one barrier per k-step, 4 blocks/CU, plain stores.
// SWAPG=1: rows on blockIdx.x (XCD row-affinity).
template <int GELU, int RES, int OUTF32, int SWAPG>
__global__ __launch_bounds__(256, 4) void gemm_bt(
    const ushort* __restrict__ A, const ushort* __restrict__ Bt,
    const float* __restrict__ bias, const float* __restrict__ resid,
    void* __restrict__ Cout, int M, int N, int K) {
    __shared__ __align__(16) __bf16 sA[2][128][32];
    __shared__ __align__(16) __bf16 sB[2][128][32];
    int tid = threadIdx.x;
    int rowBase = (SWAPG ? blockIdx.x : blockIdx.y) << 7;
    int colBase = (SWAPG ? blockIdx.y : blockIdx.x) << 7;

    int wave = tid >> 6, lane = tid & 63;
    int wm = (wave & 1) << 6, wn = (wave >> 1) << 6;
    int lrow = lane & 15, q = lane >> 4;
    int lkswz = ((q ^ ((lrow >> 1) & 3)) << 3);
    floatx4 acc[4][4] = {};

    int srow = lane >> 2;
    int schunk = (lane & 3) ^ ((lane >> 3) & 3);
    const ushort* Ag0 = A + (size_t)(rowBase + wave * 32 + srow) * K + schunk * 8;
    const ushort* Bg0 = Bt + (size_t)(colBase + wave * 32 + srow) * K + schunk * 8;
    const size_t r16 = (size_t)16 * K;
    int wr = wave * 32;

    gl_lds16(Ag0, &sA[0][wr][0]);  gl_lds16(Ag0 + r16, &sA[0][wr + 16][0]);
    gl_lds16(Bg0, &sB[0][wr][0]);  gl_lds16(Bg0 + r16, &sB[0][wr + 16][0]);
    __syncthreads();

    int nt = K >> 5;
    for (int t = 0; t < nt; t++) {
        int cur = t & 1, nb = cur ^ 1;
        if (t + 1 < nt) {
            int k0 = (t + 1) << 5;
            gl_lds16(Ag0 + k0, &sA[nb][wr][0]);  gl_lds16(Ag0 + r16 + k0, &sA[nb][wr + 16][0]);
            gl_lds16(Bg0 + k0, &sB[nb][wr][0]);  gl_lds16(Bg0 + r16 + k0, &sB[nb][wr + 16][0]);
        }
        bf16x8 af[4], bv[4];
#pragma unroll
        for (int i = 0; i < 4; i++) af[i] = *(const bf16x8*)&sA[cur][wm + i * 16 + lrow][lkswz];
#pragma unroll
        for (int jj = 0; jj < 4; jj++) bv[jj] = *(const bf16x8*)&sB[cur][wn + jj * 16 + lrow][lkswz];
#pragma unroll
        for (int i = 0; i < 4; i++)
#pragma unroll
            for (int jj = 0; jj < 4; jj++)
                acc[i][jj] = __builtin_amdgcn_mfma_f32_16x16x32_bf16(af[i], bv[jj], acc[i][jj], 0, 0, 0);
        __syncthreads();
    }
    int cr = (lane >> 4) << 2;
    int cc = lane & 15;
#pragma unroll
    for (int jj = 0; jj < 4; jj++) {
        int col = colBase + wn + jj * 16 + cc;
        float bvs = bias[col];
#pragma unroll
        for (int i = 0; i < 4; i++) {
            int row0 = rowBase + wm + i * 16 + cr;
#pragma unroll
            for (int r = 0; r < 4; r++) {
                int row = row0 + r;
                float v = acc[i][jj][r] + bvs;
                if (GELU) {
                    // 0.5u(1+tanh(z)) == u*sigmoid(2z), exact identity; HW exp
                    float u = v;
                    float z2 = -1.5957691216057308f * (u + 0.044715f * u * u * u);
                    v = u / (1.f + __expf(z2));
                }
                if (RES) v += resid[(size_t)row * N + col];
                if (OUTF32) ((float*)Cout)[(size_t)row * N + col] = v;
                else ((ushort*)Cout)[(size_t)row * N + col] = f2bf(v);
            }
        }
    }
}

// ---------- flash attention (MFMA), balanced paired q-tiles + prefetch ----------
// Q pre-split bf16 (Qhg/Qlg); K pre-scaled by sqrt(192) at qkv time.
// XCD co-location remap (r8): bi%8 = (b*4+h)%8 — group's KV shared in one L2.
// T5 setprio around MFMA clusters (m191 class: phase-diverse attn waves).
__global__ __launch_bounds__(512, 2) void attn_flash(
    const ushort* __restrict__ Qhg, const ushort* __restrict__ Qlg,
    const ushort* __restrict__ Khg, const ushort* __restrict__ Klg,
    const ushort* __restrict__ Vtg, ushort* __restrict__ attn2) {
    int bi = blockIdx.x;
    int xc = bi & 7;
    int yc = bi >> 3;
    int j  = yc & 7;
    int g  = ((yc >> 3) << 3) | xc;   // group in [0,32): g = b*4 + h
    int h  = g & 3;
    int b  = g >> 2;
    int tid = threadIdx.x;
    int wave = tid >> 6, lane = tid & 63;
    int l15 = lane & 15, quad = lane >> 4;
    int tile = (wave < 4) ? (15 - j) : j;
    int w16 = wave & 3;
    int s0 = tile << 6;
    int its = 2 * (15 - j) + 2;
    int myKt = (s0 + w16 * 16 + 15) >> 5;

    __shared__ __align__(16) __bf16 sKh[2][32][200];
    __shared__ __align__(16) __bf16 sKl[2][32][200];
    __shared__ __align__(16) __bf16 sVt[2][192][40];
    __shared__ __align__(16) ushort sP[8][16][40];

    const bool lo_half = (tid < 256);
    const int kr0 = tid / 24, ke0 = (tid % 24) * 8;
    const int c1 = lo_half ? (512 + tid) : (256 + tid);
    const int kr1 = c1 / 24, ke1 = (c1 % 24) * 8;
    const int vd0 = tid >> 2, ve0 = (tid & 3) * 8;
    const int vd1 = (512 + tid) >> 2, ve1 = ((512 + tid) & 3) * 8;

    const ushort* Khb = Khg + (size_t)(b * 1024) * 768 + h * 192;
    const ushort* Klb = Klg + (size_t)(b * 1024) * 768 + h * 192;
    const ushort* Vtb = Vtg + ((size_t)(b * 768) + h * 192) * 1024;
    const ushort* Bb = lo_half ? Khb : Klb;
    __bf16* pKB = lo_half ? &sKh[0][kr1][ke1] : &sKl[0][kr1][ke1];

    uint4 rA, rB, rC, rD, rE;

    rA = *(const uint4*)(Khb + (size_t)kr0 * 768 + ke0);
    rC = *(const uint4*)(Klb + (size_t)kr0 * 768 + ke0);
    rB = *(const uint4*)(Bb + (size_t)kr1 * 768 + ke1);
    rD = *(const uint4*)(Vtb + (size_t)vd0 * 1024 + ve0);
    if (lo_half) rE = *(const uint4*)(Vtb + (size_t)vd1 * 1024 + ve1);

    bf16x8 qh[6], ql[6];
    {
        int qrow = s0 + w16 * 16 + l15;
        const ushort* qph = Qhg + (size_t)(b * SEQ + qrow) * 768 + h * DH + quad * 8;
        const ushort* qpl = Qlg + (size_t)(b * SEQ + qrow) * 768 + h * DH + quad * 8;
#pragma unroll
        for (int dt = 0; dt < 6; dt++) {
            qh[dt] = *(const bf16x8*)(qph + dt * 32);
            ql[dt] = *(const bf16x8*)(qpl + dt * 32);
        }
    }

    floatx4 O[12] = {};
    float m_run[4], l_run[4];
#pragma unroll
    for (int r = 0; r < 4; r++) { m_run[r] = -1e30f; l_run[r] = 0.f; }

    *(uint4*)&sKh[0][kr0][ke0] = rA;
    *(uint4*)&sKl[0][kr0][ke0] = rC;
    *(uint4*)(pKB) = rB;
    *(uint4*)&sVt[0][vd0][ve0] = rD;
    if (lo_half) *(uint4*)&sVt[0][vd1][ve1] = rE;
    __syncthreads();

    for (int kt = 0; kt < its; kt++) {
        int cur = kt & 1;
        bool pfetch = (kt + 1 < its);
        if (pfetch) {
            int koff = (kt + 1) * 32;
            rA = *(const uint4*)(Khb + (size_t)(koff + kr0) * 768 + ke0);
            rC = *(const uint4*)(Klb + (size_t)(koff + kr0) * 768 + ke0);
            rB = *(const uint4*)(Bb + (size_t)(koff + kr1) * 768 + ke1);
            rD = *(const uint4*)(Vtb + (size_t)vd0 * 1024 + koff + ve0);
            if (lo_half) rE = *(const uint4*)(Vtb + (size_t)vd1 * 1024 + koff + ve1);
        }
        if (kt <= myKt) {
            floatx4 S0 = {}, S1 = {};
            __builtin_amdgcn_s_setprio(1);
#pragma unroll
            for (int dt = 0; dt < 6; dt++) {
                bf16x8 k0h = *(const bf16x8*)&sKh[cur][l15][dt * 32 + quad * 8];
                bf16x8 k0l = *(const bf16x8*)&sKl[cur][l15][dt * 32 + quad * 8];
                bf16x8 k1h = *(const bf16x8*)&sKh[cur][16 + l15][dt * 32 + quad * 8];
                bf16x8 k1l = *(const bf16x8*)&sKl[cur][16 + l15][dt * 32 + quad * 8];
                S0 = __builtin_amdgcn_mfma_f32_16x16x32_bf16(qh[dt], k0h, S0, 0, 0, 0);
                S0 = __builtin_amdgcn_mfma_f32_16x16x32_bf16(qh[dt], k0l, S0, 0, 0, 0);
                S0 = __builtin_amdgcn_mfma_f32_16x16x32_bf16(ql[dt], k0h, S0, 0, 0, 0);
                S1 = __builtin_amdgcn_mfma_f32_16x16x32_bf16(qh[dt], k1h, S1, 0, 0, 0);
                S1 = __builtin_amdgcn_mfma_f32_16x16x32_bf16(qh[dt], k1l, S1, 0, 0, 0);
                S1 = __builtin_amdgcn_mfma_f32_16x16x32_bf16(ql[dt], k1h, S1, 0, 0, 0);
            }
            __builtin_amdgcn_s_setprio(0);
            int qg = s0 + w16 * 16 + quad * 4;
            int colb = kt * 32 + l15;
            float mt[4];
#pragma unroll
            for (int r = 0; r < 4; r++) {
                float a = (colb <= qg + r) ? S0[r] : -1e30f;
                float c = (colb + 16 <= qg + r) ? S1[r] : -1e30f;
                S0[r] = a; S1[r] = c;
                mt[r] = fmaxf(a, c);
            }
#pragma unroll
            for (int m = 1; m <= 8; m <<= 1)
#pragma unroll
                for (int r = 0; r < 4; r++) mt[r] = fmaxf(mt[r], __shfl_xor(mt[r], m));
            float alpha[4], rsum[4], P0[4], P1[4];
#pragma unroll
            for (int r = 0; r < 4; r++) {
                float mn = fmaxf(m_run[r], mt[r]);
                alpha[r] = __expf(m_run[r] - mn);
                m_run[r] = mn;
                P0[r] = __expf(S0[r] - mn);
                P1[r] = __expf(S1[r] - mn);
                rsum[r] = P0[r] + P1[r];
            }
#pragma unroll
            for (int m = 1; m <= 8; m <<= 1)
#pragma unroll
                for (int r = 0; r < 4; r++) rsum[r] += __shfl_xor(rsum[r], m);
#pragma unroll
            for (int r = 0; r < 4; r++) l_run[r] = l_run[r] * alpha[r] + rsum[r];
#pragma unroll
            for (int t = 0; t < 12; t++)
#pragma unroll
                for (int r = 0; r < 4; r++) O[t][r] *= alpha[r];
#pragma unroll
            for (int r = 0; r < 4; r++) {
                sP[wave][quad * 4 + r][l15]      = f2bf(P0[r]);
                sP[wave][quad * 4 + r][16 + l15] = f2bf(P1[r]);
            }
            bf16x8 pfrag = *(const bf16x8*)&sP[wave][l15][quad * 8];
            __builtin_amdgcn_s_setprio(1);
#pragma unroll
            for (int t = 0; t < 12; t++) {
                bf16x8 vf = *(const bf16x8*)&sVt[cur][t * 16 + l15][quad * 8];
                O[t] = __builtin_amdgcn_mfma_f32_16x16x32_bf16(pfrag, vf, O[t], 0, 0, 0);
            }
            __builtin_amdgcn_s_setprio(0);
        }
        if (pfetch) {
            int nb = cur ^ 1;
            *(uint4*)&sKh[nb][kr0][ke0] = rA;
            *(uint4*)&sKl[nb][kr0][ke0] = rC;
            *(uint4*)(pKB + nb * 6400) = rB;
            *(uint4*)&sVt[nb][vd0][ve0] = rD;
            if (lo_half) *(uint4*)&sVt[nb][vd1][ve1] = rE;
        }
        __syncthreads();
    }

    float inv[4];
#pragma unroll
    for (int r = 0; r < 4; r++) inv[r] = 1.f / l_run[r];
    int qrow = s0 + w16 * 16 + quad * 4;
#pragma unroll
    for (int t = 0; t < 12; t++)
#pragma unroll
        for (int r = 0; r < 4; r++)
            attn2[(size_t)(b * SEQ + qrow + r) * D_MODEL + h * DH + t * 16 + l15] =
                f2bf(O[t][r] * inv[r]);
}

extern "C" void kernel_launch(void* const* d_in, const int* in_sizes, int n_in,
                              void* d_out, int out_size, void* d_ws, size_t ws_size,
                              hipStream_t stream) {
    const float* x  = (const float*)d_in[0];
    const float* W1 = (const float*)d_in[2];
    const float* b1 = (const float*)d_in[3];
    const float* W3 = (const float*)d_in[4];
    const float* b3 = (const float*)d_in[5];
    const float* W2 = (const float*)d_in[6];
    const float* b2 = (const float*)d_in[7];
    const float* W4 = (const float*)d_in[8];
    const float* b4 = (const float*)d_in[9];
    const float* g1 = (const float*)d_in[10];
    const float* be1 = (const float*)d_in[11];
    const float* g2 = (const float*)d_in[12];
    const float* be2 = (const float*)d_in[13];

    // ---- ws layout, lifetime-aliased ----
    char* ws = (char*)d_ws;
    ushort* W1t_hi = (ushort*)(ws + 0);            // -> 3,538,944
    ushort* W1t_lo = (ushort*)(ws + 3538944);      // -> 7,077,888
    ushort* W3t    = (ushort*)(ws + 7077888);      // -> 8,257,536
    ushort* W2t    = (ushort*)(ws + 8257536);      // -> 12,976,128
    ushort* W4t    = (ushort*)(ws + 12976128);     // -> 17,694,720
    ushort* xn_hi  = (ushort*)(ws + 17694720);     // -> 30,277,632 (then attn2)
    ushort* attn2  = (ushort*)(ws + 17694720);
    ushort* xn_lo  = (ushort*)(ws + 30277632);     // -> 42,860,544 (then xn2)
    ushort* xn2    = (ushort*)(ws + 30277632);
    ushort* Qhg    = (ushort*)(ws + 42860544);     // -> 55,443,456 (dead after attn)
    ushort* Qlg    = (ushort*)(ws + 55443456);     // -> 68,026,368 (dead after attn)
    ushort* hbuf   = (ushort*)(ws + 42860544);     // ff1 out: -> 93,192,192
    ushort* Khg    = (ushort*)(ws + 68026368);     // -> 80,609,280 (dead after attn)
    ushort* Klg    = (ushort*)(ws + 80609280);     // -> 93,192,192 (dead after attn)
    ushort* Vtg    = (ushort*)(ws + 93192192);     // -> 105,775,104 (dead after attn)
    float*  x1     = (float*)(ws + 105775104);     // -> 130,940,928

    float* out0 = (float*)d_out;
    float* present = out0 + 6291456;

    // fused: weight transposes (1728 blocks) + ln1 (8192 blocks)
    prep_kernel<<<1728 + 8192, 256, 0, stream>>>(
        W1, W1t_hi, W1t_lo, W3, W3t, W2, W2t, W4, W4t, x, g1, be1, xn_hi, xn_lo);
    // rows on x (fast axis): bid%8 = row%8 -> per-XCD A-panel residency
    gemm_qkv_split<<<dim3(8192 / 128, 2304 / 128), 256, 0, stream>>>(
        xn_hi, xn_lo, W1t_hi, W1t_lo, b1, Qhg, Qlg, present, Khg, Klg, Vtg);
    attn_flash<<<BATCH * NH * 8, 512, 0, stream>>>(Qhg, Qlg, Khg, Klg, Vtg, attn2);
    // proj: SWAPG=1 (A/XCD = 1.6MB, L2-fit)
    gemm_bt<0, 1, 1, 1><<<dim3(8192 / 128, 768 / 128), 256, 0, stream>>>(
        attn2, W3t, b3, x, x1, 8192, 768, 768);
    ln_kernel<0><<<8192, 256, 0, stream>>>(x1, g2, be2, xn2, nullptr);
    // ff1: SWAPG=1 (A/XCD = 1.6MB, L2-fit)
    gemm_bt<1, 0, 0, 1><<<dim3(8192 / 128, 3072 / 128), 256, 0, stream>>>(
        xn2, W2t, b2, nullptr, hbuf, 8192, 3072, 768);
    // ff2: SWAPG=1 row-affinity (B streams 4.7MB x8 = 38MB; A rides L3)
    gemm_bt<0, 1, 1, 1><<<dim3(8192 / 128, 3072 / 128 / 4), 256, 0, stream>>>(
        hbuf, W4t, b4, x1, out0, 8192, 768, 3072);
}